// Round 2
// baseline (8797.210 us; speedup 1.0000x reference)
//
#include <hip/hip_runtime.h>
#include <hip/hip_cooperative_groups.h>
#include <math.h>

namespace cg = cooperative_groups;

#define H 512
#define D2 1024
#define D4 2048
#define E 1024
#define V 32000
#define M 32
#define N 4096
#define L 64
#define G3 (3*D4)   // 6144

// workspace layout (float offsets)
#define WS_H        0                      // 1024
#define WS_UAH      1024                   // 1024
#define WS_HSEQ     2048                   // 65*2048 = 133120
#define WS_GIW      135168                 // 64*6144 = 393216 (dead after steps; overlaid below)
#define WS_RW       528384                 // 64*1024 = 65536
#define WS_GH2      593920                 // 2 parity * 6144
#define WS_GIC0     606208                 // 2 * 6144
#define WS_GIC1     618496                 // 2 * 6144
#define WS_AT       630784                 // 128 floats: a0,a1 per step
#define WS_SP0      634880                 // 2 * 256
#define WS_SP1      635392                 // 2 * 256
#define WS_RT       635904                 // 512*64 (transposed r for logits GEMM)
#define WS_ANST     668672                 // 1024*64 (ans transposed)
// overlays of the dead WS_GIW region (valid only after the step loop):
#define WS_CT       WS_GIW                 // 1024*64 = 65536   (c_t columns, k-major)
#define WS_HST      (WS_GIW + 65536)       // 2048*64 = 131072  (h(t+1) columns, k-major)
#define WS_R3       (WS_GIW + 196608)      // 3*1024*64 = 196608 (K-split partials)
#define WS_BLOCKMAX WS_GIW                 // 64 rows * 256 block maxima (logits phase, after CT dead)
// bf16 weight caches (optional, if ws_size permits)
#define WS_WHHB     734208                 // 6144*2048 bf16 = 6291456 floats
#define WS_WIHCB    7025664                // 6144*1024 bf16 = 3145728 floats
#define WS_END_BF   10171392               // total floats with bf16 caches (~40.7 MB)

__device__ __forceinline__ float warpSum64(float v){
#pragma unroll
    for (int off = 32; off; off >>= 1) v += __shfl_xor(v, off, 64);
    return v;
}
__device__ __forceinline__ float dot4(float4 a, float4 b){
    return a.x*b.x + a.y*b.y + a.z*b.z + a.w*b.w;
}
__device__ __forceinline__ unsigned short f2bf(float f){
    unsigned u = __float_as_uint(f);
    u += 0x7fffu + ((u >> 16) & 1u);   // RNE
    return (unsigned short)(u >> 16);
}
__device__ __forceinline__ float bflo(unsigned u){ return __uint_as_float(u << 16); }
__device__ __forceinline__ float bfhi(unsigned u){ return __uint_as_float(u & 0xffff0000u); }

// ---------------- init: transpose ans, zero h ----------------
__global__ void k_init(const float* __restrict__ ans, float* __restrict__ ws){
    int b = blockIdx.x;
    if (b < L){
        for (int j = threadIdx.x; j < E; j += blockDim.x)
            ws[WS_ANST + j*L + b] = ans[b*E + j];
    } else {
        for (int i = threadIdx.x; i < D2; i += blockDim.x) ws[WS_H + i] = 0.f;
    }
}

// ---------------- one-time bf16 conversion of whh + wih c-half ----------------
__global__ __launch_bounds__(256) void k_cvt(const float* __restrict__ whh,
        const float* __restrict__ wih, float* __restrict__ ws){
    size_t idx = (size_t)blockIdx.x*blockDim.x + threadIdx.x;
    size_t nthr = (size_t)gridDim.x*blockDim.x;
    ushort4* dw = (ushort4*)(ws + WS_WHHB);
    const float4* s4 = (const float4*)whh;
    for (size_t i = idx; i < (size_t)G3*D4/4; i += nthr){
        float4 v = s4[i];
        ushort4 o; o.x = f2bf(v.x); o.y = f2bf(v.y); o.z = f2bf(v.z); o.w = f2bf(v.w);
        dw[i] = o;
    }
    ushort4* dc = (ushort4*)(ws + WS_WIHCB);
    const float4* w4 = (const float4*)wih;
    for (size_t i = idx; i < (size_t)G3*D2/4; i += nthr){
        size_t row = i / (D2/4), col = i - row*(D2/4);
        float4 v = w4[row*(D4/4) + (D2/4) + col];
        ushort4 o; o.x = f2bf(v.x); o.y = f2bf(v.y); o.z = f2bf(v.z); o.w = f2bf(v.w);
        dc[i] = o;
    }
}

// ---------------- h = colsum(h_q) + colsum(h_p) ----------------
__global__ void k_colsum(const float* __restrict__ hq, const float* __restrict__ hp,
                         float* __restrict__ ws){
    float4 acc = {0.f,0.f,0.f,0.f};
    int tid = threadIdx.x;
    for (int r = blockIdx.x; r < M + N; r += gridDim.x){
        const float* src = (r < M) ? (hq + (size_t)r*D2) : (hp + (size_t)(r-M)*D2);
        float4 v = ((const float4*)src)[tid];
        acc.x += v.x; acc.y += v.y; acc.z += v.z; acc.w += v.w;
    }
    float* h = ws + WS_H + tid*4;
    atomicAdd(h+0, acc.x); atomicAdd(h+1, acc.y);
    atomicAdd(h+2, acc.z); atomicAdd(h+3, acc.w);
}

// ---------------- u_a_h and d0 ----------------
__global__ __launch_bounds__(256) void k_uah_d0(
        const float* __restrict__ uaw, const float* __restrict__ wdw,
        const float* __restrict__ wdb, const float* __restrict__ hq,
        const float* __restrict__ hp, float* __restrict__ ws){
    int wid = blockIdx.x * (blockDim.x >> 6) + (threadIdx.x >> 6);
    int lane = threadIdx.x & 63;
    const float* Wrow; const float* x;
    if (wid < D2){ Wrow = uaw + (size_t)wid*D2; x = ws + WS_H; }
    else {
        int i = (wid - D2) & 1023;
        int r = (wid - D2) >> 10;
        Wrow = wdw + (size_t)i*D2;
        x = r ? hp : hq;
    }
    const float4* W4 = (const float4*)Wrow;
    const float4* x4 = (const float4*)x;
    float acc = 0.f;
#pragma unroll
    for (int m = 0; m < 4; m++){
        int j = lane + 64*m;
        acc += dot4(W4[j], x4[j]);
    }
    acc = warpSum64(acc);
    if (lane == 0){
        if (wid < D2) ws[WS_UAH + wid] = acc;
        else {
            int i = (wid - D2) & 1023, r = (wid - D2) >> 10;
            ws[WS_HSEQ + r*D2 + i] = tanhf(acc + wdb[i]);
        }
    }
}

// ---------------- pregemm as tiled GEMM (conflict-free, 224 blocks) ----------------
// C[7168][64] = W[7168][1024] @ ansT[1024][64]
// blocks 0..191: wih w-half 32-row tiles -> GIW (+bias); 192..223: wrw -> RW
__global__ __launch_bounds__(256) void k_pregemm(
        const float* __restrict__ wih, const float* __restrict__ bih,
        const float* __restrict__ wrw, float* __restrict__ ws){
    __shared__ float aR[32][68];    // [row][k] row-major: conflict-free stores, broadcast reads
    __shared__ float b_s[64][68];   // [k][t]
    int tid = threadIdx.x;
    int blk = blockIdx.x;
    bool isW = blk < 192;
    const float* src = isW ? wih : wrw;
    size_t stride = isW ? D4 : D2;
    int rbase = isW ? blk*32 : (blk-192)*32;
    int t0 = (tid & 15) * 4;
    int rg = (tid >> 4) * 2;
    float acc[4][2];
#pragma unroll
    for (int i = 0; i < 4; i++){ acc[i][0] = 0.f; acc[i][1] = 0.f; }

    const float* ansT = ws + WS_ANST;
    for (int kc = 0; kc < 1024; kc += 64){
        __syncthreads();
#pragma unroll
        for (int it = 0; it < 2; it++){
            int idx = it*256 + tid;
            int row = idx >> 4;
            int kq  = (idx & 15) * 4;
            float4 w = *(const float4*)(src + (size_t)(rbase + row)*stride + kc + kq);
            *(float4*)&aR[row][kq] = w;
        }
#pragma unroll
        for (int it = 0; it < 4; it++){
            int idx = it*256 + tid;
            int k = idx >> 4;
            int c4 = (idx & 15) * 4;
            *(float4*)&b_s[k][c4] = *(const float4*)(ansT + (size_t)(kc + k)*L + c4);
        }
        __syncthreads();
#pragma unroll 4
        for (int k = 0; k < 64; k++){
            float4 bb = *(float4*)&b_s[k][t0];
            float a0r = aR[rg][k], a1r = aR[rg+1][k];
            acc[0][0] += bb.x*a0r; acc[0][1] += bb.x*a1r;
            acc[1][0] += bb.y*a0r; acc[1][1] += bb.y*a1r;
            acc[2][0] += bb.z*a0r; acc[2][1] += bb.z*a1r;
            acc[3][0] += bb.w*a0r; acc[3][1] += bb.w*a1r;
        }
    }
#pragma unroll
    for (int i = 0; i < 4; i++){
#pragma unroll
        for (int j = 0; j < 2; j++){
            int r = rbase + rg + j;
            if (isW) ws[WS_GIW + (size_t)(t0+i)*G3 + r] = acc[i][j] + bih[r];
            else     ws[WS_RW  + (size_t)(t0+i)*D2 + r] = acc[i][j];
        }
    }
}

// ---------------- persistent step kernel: ALL 64 steps, one grid-sync per step ------
// tasks per step: [0,256) s | [256,6400) gh | [6400,12544) giC
#define STEP_BLOCKS 256
#define STEP_THREADS 1024
#define NWAVES (STEP_BLOCKS*16)
#define STEP_TASKS 12544
__global__ __launch_bounds__(1024) void k_steps(
        const float* __restrict__ whh, const float* __restrict__ bhh,
        const float* __restrict__ wih, const float* __restrict__ waw,
        const float* __restrict__ vw,  float* __restrict__ ws, int use_bf){
    cg::grid_group grid = cg::this_grid();
    __shared__ float4 h4s[D4/4];
    __shared__ float red[16];
    __shared__ float sa[2];
    float* h_lds = (float*)h4s;
    int tid = threadIdx.x, lane = tid & 63, wv = tid >> 6;
    bool blk0 = (blockIdx.x == 0);

    for (int t = 0; t <= L; ++t){
        int par = t & 1, pprev = par ^ 1;

        // ---- a(t-1) from spart(t-1) ----
        if (t >= 1){
            if (wv < 8){
                float x = ws[(wv < 4 ? WS_SP0 : WS_SP1) + pprev*256 + (wv & 3)*64 + lane];
                x = warpSum64(x);
                if (lane == 0) red[wv] = x;
            }
            __syncthreads();
            if (tid == 0){
                float s0 = red[0]+red[1]+red[2]+red[3];
                float s1 = red[4]+red[5]+red[6]+red[7];
                float mx = fmaxf(s0, s1);
                float e0 = expf(s0-mx), e1 = expf(s1-mx);
                sa[0] = e0/(e0+e1); sa[1] = e1/(e0+e1);
                if (blk0){
                    ws[WS_AT + (t-1)*2]     = sa[0];
                    ws[WS_AT + (t-1)*2 + 1] = sa[1];
                }
            }
            __syncthreads();
        }
        float a0 = (t >= 1) ? sa[0] : 0.f;
        float a1 = (t >= 1) ? sa[1] : 0.f;

        // ---- reconstruct h(t) into LDS (hprev comes from our own LDS) ----
        if (t == 0){
            for (int i = tid; i < D4; i += STEP_THREADS) h_lds[i] = ws[WS_HSEQ + i];
        } else {
            const float* giw = ws + WS_GIW + (size_t)(t-1)*G3;
            const float* gh  = ws + WS_GH2  + pprev*G3;
            const float* g0  = ws + WS_GIC0 + pprev*G3;
            const float* g1  = ws + WS_GIC1 + pprev*G3;
            for (int k = tid; k < D4; k += STEP_THREADS){
                float hp = h_lds[k];                      // h(t-1), ours from last iter
                float gir = giw[k]      + a0*g0[k]      + a1*g1[k];
                float giz = giw[k+D4]   + a0*g0[k+D4]   + a1*g1[k+D4];
                float gin = giw[k+2*D4] + a0*g0[k+2*D4] + a1*g1[k+2*D4];
                float rr = 1.f/(1.f + expf(-(gir + gh[k])));
                float zz = 1.f/(1.f + expf(-(giz + gh[k+D4])));
                float nn = tanhf(gin + rr*gh[k+2*D4]);
                float hv = (1.f - zz)*nn + zz*hp;
                h_lds[k] = hv;
                if (blk0) ws[WS_HSEQ + (size_t)t*D4 + k] = hv;
            }
        }
        __syncthreads();

        if (t >= L) break;   // final iteration only reconstructs h(64) / stores a(63)

        // ---- GEMV task phase ----
        const float4* h4 = (const float4*)h_lds;
        int gw = blockIdx.x*16 + wv;
        for (int task = gw; task < STEP_TASKS; task += NWAVES){
            if (task < 256){
                int g = task;
                float p0 = 0.f, p1 = 0.f;
                for (int ii = 0; ii < 4; ii++){
                    int i = g*4 + ii;
                    const float4* W4 = (const float4*)(waw + (size_t)i*D2);
                    float ac0 = 0.f, ac1 = 0.f;
#pragma unroll
                    for (int m = 0; m < 4; m++){
                        int j = lane + 64*m;
                        float4 w = W4[j];
                        ac0 += dot4(w, h4[j]);
                        ac1 += dot4(w, h4[256 + j]);
                    }
                    ac0 = warpSum64(ac0); ac1 = warpSum64(ac1);
                    if (lane == 0){
                        float u = ws[WS_UAH + i], vv = vw[i];
                        p0 += vv * tanhf(ac0 + u);
                        p1 += vv * tanhf(ac1 + u);
                    }
                }
                if (lane == 0){
                    ws[WS_SP0 + par*256 + g] = p0;
                    ws[WS_SP1 + par*256 + g] = p1;
                }
            } else if (task < 6400){
                int k = task - 256;     // gh
                float acc = 0.f;
                if (use_bf){
                    const unsigned short* Wr = (const unsigned short*)(ws + WS_WHHB) + (size_t)k*D4;
#pragma unroll
                    for (int m = 0; m < 4; m++){
                        int e = m*512 + lane*8;
                        uint4 w = *(const uint4*)(Wr + e);
                        float4 ha = h4[e>>2], hb = h4[(e>>2)+1];
                        acc += bflo(w.x)*ha.x + bfhi(w.x)*ha.y
                             + bflo(w.y)*ha.z + bfhi(w.y)*ha.w
                             + bflo(w.z)*hb.x + bfhi(w.z)*hb.y
                             + bflo(w.w)*hb.z + bfhi(w.w)*hb.w;
                    }
                } else {
                    const float4* W4 = (const float4*)(whh + (size_t)k*D4);
#pragma unroll
                    for (int m = 0; m < 8; m++){
                        int j = lane + 64*m;
                        acc += dot4(W4[j], h4[j]);
                    }
                }
                acc = warpSum64(acc);
                if (lane == 0) ws[WS_GH2 + par*G3 + k] = acc + bhh[k];
            } else {
                int k = task - 6400;     // giC dual (wih c-half)
                float ac0 = 0.f, ac1 = 0.f;
                if (use_bf){
                    const unsigned short* Wr = (const unsigned short*)(ws + WS_WIHCB) + (size_t)k*D2;
#pragma unroll
                    for (int m = 0; m < 2; m++){
                        int e = m*512 + lane*8;
                        uint4 w = *(const uint4*)(Wr + e);
                        float4 ha = h4[e>>2],       hb = h4[(e>>2)+1];
                        float4 hc = h4[256+(e>>2)], hd = h4[256+(e>>2)+1];
                        float f0 = bflo(w.x), f1 = bfhi(w.x), f2 = bflo(w.y), f3 = bfhi(w.y);
                        float f4 = bflo(w.z), f5 = bfhi(w.z), f6 = bflo(w.w), f7 = bfhi(w.w);
                        ac0 += f0*ha.x + f1*ha.y + f2*ha.z + f3*ha.w
                             + f4*hb.x + f5*hb.y + f6*hb.z + f7*hb.w;
                        ac1 += f0*hc.x + f1*hc.y + f2*hc.z + f3*hc.w
                             + f4*hd.x + f5*hd.y + f6*hd.z + f7*hd.w;
                    }
                } else {
                    const float4* W4 = (const float4*)(wih + (size_t)k*D4 + D2);
#pragma unroll
                    for (int m = 0; m < 4; m++){
                        int j = lane + 64*m;
                        float4 w = W4[j];
                        ac0 += dot4(w, h4[j]);
                        ac1 += dot4(w, h4[256 + j]);
                    }
                }
                ac0 = warpSum64(ac0); ac1 = warpSum64(ac1);
                if (lane == 0){
                    ws[WS_GIC0 + par*G3 + k] = ac0;
                    ws[WS_GIC1 + par*G3 + k] = ac1;
                }
            }
        }

        __threadfence();   // make gh/giC/sp visible device-wide before the barrier
        grid.sync();
    }
}

// ---------------- prep for deferred r: build CT[k][t] and HST[k][t] ----------------
// CT[:,j] = a0(j)*h(j)[0:D2] + a1(j)*h(j)[D2:2*D2];  HST[:,j] = h(j+1)
__global__ __launch_bounds__(256) void k_prep(float* __restrict__ ws){
    int j = blockIdx.x;            // 0..63
    const float* hA = ws + WS_HSEQ + (size_t)j*D4;
    const float* hB = hA + D4;
    float a0 = ws[WS_AT + 2*j], a1 = ws[WS_AT + 2*j + 1];
    for (int k = threadIdx.x; k < D4; k += 256){
        ws[WS_HST + (size_t)k*64 + j] = hB[k];
        if (k < D2) ws[WS_CT + (size_t)k*64 + j] = a0*hA[k] + a1*hA[k + D2];
    }
}

// ---------------- deferred r GEMM: R_partial = Urw@CT (ks=0) | Vrw@HST halves (ks=1,2) ----
// grid 48 = 16 h-blocks x 3 K-splits; each block: 64 A-rows (32 top h + 32 bottom h+512) x 64 t
__global__ __launch_bounds__(512) void k_post(const float* __restrict__ urw,
        const float* __restrict__ vrw, float* __restrict__ ws){
    __shared__ float aR[64][68];
    __shared__ float bS[64][68];
    int tid = threadIdx.x;
    int hb = blockIdx.x & 15;
    int ks = blockIdx.x >> 4;          // 0: urw/CT; 1,2: vrw/HST halves
    int hbase = hb * 32;
    const float* A = (ks == 0) ? urw : vrw;
    size_t astride = (ks == 0) ? D2 : D4;
    int koff = (ks == 2) ? 1024 : 0;
    const float* B = ws + ((ks == 0) ? WS_CT : WS_HST) + (size_t)koff*64;
    int tg = tid & 15, vg = tid >> 4;   // vg in [0,32)
    int t0 = tg*4;
    int r0 = vg*2;
    float acc[2][4];
#pragma unroll
    for (int j = 0; j < 2; j++){ acc[j][0]=acc[j][1]=acc[j][2]=acc[j][3]=0.f; }

    for (int kc = 0; kc < 1024; kc += 64){
        __syncthreads();
#pragma unroll
        for (int it = 0; it < 2; it++){
            int idx = it*512 + tid;
            int r = idx >> 4;
            int kq = (idx & 15) * 4;
            int grow = (r < 32) ? (hbase + r) : (512 + hbase + (r - 32));
            *(float4*)&aR[r][kq] = *(const float4*)(A + (size_t)grow*astride + koff + kc + kq);
        }
#pragma unroll
        for (int it = 0; it < 2; it++){
            int idx = it*512 + tid;
            int k = idx >> 4;
            int c4 = (idx & 15)*4;
            *(float4*)&bS[k][c4] = *(const float4*)(B + (size_t)(kc + k)*64 + c4);
        }
        __syncthreads();
#pragma unroll 4
        for (int k = 0; k < 64; k++){
            float4 bb = *(float4*)&bS[k][t0];
            float a0 = aR[r0][k], a1 = aR[r0+1][k];
            acc[0][0]+=bb.x*a0; acc[0][1]+=bb.y*a0; acc[0][2]+=bb.z*a0; acc[0][3]+=bb.w*a0;
            acc[1][0]+=bb.x*a1; acc[1][1]+=bb.y*a1; acc[1][2]+=bb.z*a1; acc[1][3]+=bb.w*a1;
        }
    }
    float* R = ws + WS_R3 + (size_t)ks*65536;
#pragma unroll
    for (int j = 0; j < 2; j++){
        int r = r0 + j;
        int grow = (r < 32) ? (hbase + r) : (512 + hbase + (r - 32));
        float4 o = {acc[j][0], acc[j][1], acc[j][2], acc[j][3]};
        *(float4*)(R + (size_t)grow*64 + t0) = o;
    }
}

// ---------------- combine partials + RW, maxout -> RT (transposed for logits) ----------
__global__ __launch_bounds__(256) void k_rmax(float* __restrict__ ws){
    int tid = threadIdx.x;
    int h = blockIdx.x*16 + (tid >> 4);   // 32 blocks -> 512 h
    int t0 = (tid & 15)*4;
    const float* R = ws + WS_R3;
    float4 x0 = *(const float4*)(R + (size_t)h*64 + t0);
    float4 x1 = *(const float4*)(R + 65536 + (size_t)h*64 + t0);
    float4 x2 = *(const float4*)(R + 131072 + (size_t)h*64 + t0);
    float4 y0 = *(const float4*)(R + (size_t)(h+512)*64 + t0);
    float4 y1 = *(const float4*)(R + 65536 + (size_t)(h+512)*64 + t0);
    float4 y2 = *(const float4*)(R + 131072 + (size_t)(h+512)*64 + t0);
    float4 o;
    o.x = fmaxf(x0.x+x1.x+x2.x + ws[WS_RW + (size_t)(t0+0)*D2 + h],
                y0.x+y1.x+y2.x + ws[WS_RW + (size_t)(t0+0)*D2 + h + 512]);
    o.y = fmaxf(x0.y+x1.y+x2.y + ws[WS_RW + (size_t)(t0+1)*D2 + h],
                y0.y+y1.y+y2.y + ws[WS_RW + (size_t)(t0+1)*D2 + h + 512]);
    o.z = fmaxf(x0.z+x1.z+x2.z + ws[WS_RW + (size_t)(t0+2)*D2 + h],
                y0.z+y1.z+y2.z + ws[WS_RW + (size_t)(t0+2)*D2 + h + 512]);
    o.w = fmaxf(x0.w+x1.w+x2.w + ws[WS_RW + (size_t)(t0+3)*D2 + h],
                y0.w+y1.w+y2.w + ws[WS_RW + (size_t)(t0+3)*D2 + h + 512]);
    *(float4*)(ws + WS_RT + (size_t)h*L + t0) = o;
}

// ---------------- logits GEMM: out[t][v] = w_o[v] . r_t (tiled, coalesced) ----------------
__global__ __launch_bounds__(256) void k_logits(const float* __restrict__ wo,
        float* __restrict__ out, float* __restrict__ ws){
    __shared__ float a_s[64][132];
    __shared__ float b_s[64][68];
    __shared__ float lmax[64][16];
    int tid = threadIdx.x;
    int vbase = blockIdx.x * 128;
    int tg = tid & 15;
    int vg = tid >> 4;
    int t0 = tg * 4, v0 = vg * 8;
    float acc[4][8];
#pragma unroll
    for (int i = 0; i < 4; i++)
#pragma unroll
        for (int j = 0; j < 8; j++) acc[i][j] = 0.f;

    const float* rT = ws + WS_RT;
    for (int kc = 0; kc < 512; kc += 64){
        __syncthreads();
        {
            int col = (tid & 15) * 4;
            int rbase = tid >> 4;
#pragma unroll
            for (int it = 0; it < 8; it++){
                int r = it*16 + rbase;
                float4 w = *(const float4*)(wo + (size_t)(vbase + r)*H + kc + col);
                a_s[col+0][r] = w.x; a_s[col+1][r] = w.y;
                a_s[col+2][r] = w.z; a_s[col+3][r] = w.w;
            }
#pragma unroll
            for (int it = 0; it < 4; it++){
                int idx = it*256 + tid;
                int k = idx >> 4;
                int c4 = (idx & 15) * 4;
                *(float4*)&b_s[k][c4] = *(const float4*)(rT + (size_t)(kc + k)*L + c4);
            }
        }
        __syncthreads();
#pragma unroll 4
        for (int k = 0; k < 64; k++){
            float4 bb = *(float4*)&b_s[k][t0];
            float4 aa = *(float4*)&a_s[k][v0];
            float4 ab = *(float4*)&a_s[k][v0+4];
            float bv[4] = {bb.x, bb.y, bb.z, bb.w};
            float av[8] = {aa.x, aa.y, aa.z, aa.w, ab.x, ab.y, ab.z, ab.w};
#pragma unroll
            for (int i = 0; i < 4; i++)
#pragma unroll
                for (int j = 0; j < 8; j++) acc[i][j] += bv[i]*av[j];
        }
    }
#pragma unroll
    for (int i = 0; i < 4; i++){
        float m = acc[i][0];
#pragma unroll
        for (int j = 1; j < 8; j++) m = fmaxf(m, acc[i][j]);
        lmax[t0+i][vg] = m;
        float4 o1 = {acc[i][0], acc[i][1], acc[i][2], acc[i][3]};
        float4 o2 = {acc[i][4], acc[i][5], acc[i][6], acc[i][7]};
        float* dst = out + (size_t)(t0+i)*V + vbase + v0;
        *(float4*)dst = o1;
        *(float4*)(dst+4) = o2;
    }
    __syncthreads();
    if (tid < 64){
        float m = lmax[tid][0];
#pragma unroll
        for (int j = 1; j < 16; j++) m = fmaxf(m, lmax[tid][j]);
        ws[WS_BLOCKMAX + (size_t)tid*256 + blockIdx.x] = m;
    }
}

// ---------------- softmax per row ----------------
__global__ __launch_bounds__(1024) void k_softmax(float* __restrict__ out,
                                                  const float* __restrict__ ws){
    __shared__ float red[16];
    __shared__ float bcast;
    int t = blockIdx.x, tid = threadIdx.x;
    int lane = tid & 63, wv = tid >> 6;
    float m = -3.402823466e38f;
    if (tid < 250) m = ws[WS_BLOCKMAX + (size_t)t*256 + tid];
#pragma unroll
    for (int off = 32; off; off >>= 1) m = fmaxf(m, __shfl_xor(m, off, 64));
    if (lane == 0) red[wv] = m;
    __syncthreads();
    if (tid == 0){
        float mm = red[0];
        for (int i = 1; i < 16; i++) mm = fmaxf(mm, red[i]);
        bcast = mm;
    }
    __syncthreads();
    float rmax = bcast;
    float* row = out + (size_t)t*V;
    float4 e[8];
    float s = 0.f;
#pragma unroll
    for (int i = 0; i < 8; i++){
        int idx = tid + i*1024;
        if (idx < V/4){
            float4 x = ((const float4*)row)[idx];
            e[i].x = expf(x.x - rmax); e[i].y = expf(x.y - rmax);
            e[i].z = expf(x.z - rmax); e[i].w = expf(x.w - rmax);
            s += e[i].x + e[i].y + e[i].z + e[i].w;
        }
    }
#pragma unroll
    for (int off = 32; off; off >>= 1) s += __shfl_xor(s, off, 64);
    if (lane == 0) red[wv] = s;
    __syncthreads();
    if (tid == 0){
        float ss = 0.f;
        for (int i = 0; i < 16; i++) ss += red[i];
        bcast = 1.f/ss;
    }
    __syncthreads();
    float inv = bcast;
#pragma unroll
    for (int i = 0; i < 8; i++){
        int idx = tid + i*1024;
        if (idx < V/4){
            float4 p = e[i];
            p.x *= inv; p.y *= inv; p.z *= inv; p.w *= inv;
            ((float4*)row)[idx] = p;
        }
    }
}

extern "C" void kernel_launch(void* const* d_in, const int* in_sizes, int n_in,
                              void* d_out, int out_size, void* d_ws, size_t ws_size,
                              hipStream_t stream){
    const float* hq  = (const float*)d_in[0];
    const float* hp  = (const float*)d_in[1];
    const float* ans = (const float*)d_in[2];
    const float* vw  = (const float*)d_in[3];
    const float* wdw = (const float*)d_in[4];
    const float* wdb = (const float*)d_in[5];
    const float* waw = (const float*)d_in[6];
    const float* uaw = (const float*)d_in[7];
    const float* wrw = (const float*)d_in[8];
    const float* urw = (const float*)d_in[9];
    const float* vrw = (const float*)d_in[10];
    const float* wo  = (const float*)d_in[11];
    const float* wih = (const float*)d_in[12];
    const float* whh = (const float*)d_in[13];
    const float* bih = (const float*)d_in[14];
    const float* bhh = (const float*)d_in[15];
    float* out = (float*)d_out;
    float* ws  = (float*)d_ws;

    int use_bf = (ws_size >= (size_t)WS_END_BF * 4) ? 1 : 0;

    k_init<<<L+1, 256, 0, stream>>>(ans, ws);
    if (use_bf) k_cvt<<<1024, 256, 0, stream>>>(whh, wih, ws);
    k_colsum<<<256, 256, 0, stream>>>(hq, hp, ws);
    k_uah_d0<<<768, 256, 0, stream>>>(uaw, wdw, wdb, hq, hp, ws);
    k_pregemm<<<224, 256, 0, stream>>>(wih, bih, wrw, ws);

    {
        void* args[] = {(void*)&whh, (void*)&bhh, (void*)&wih, (void*)&waw,
                        (void*)&vw, (void*)&ws, (void*)&use_bf};
        hipLaunchCooperativeKernel((void*)k_steps, dim3(STEP_BLOCKS),
                                   dim3(STEP_THREADS), args, 0, stream);
    }

    k_prep<<<L, 256, 0, stream>>>(ws);
    k_post<<<48, 512, 0, stream>>>(urw, vrw, ws);
    k_rmax<<<32, 256, 0, stream>>>(ws);

    k_logits<<<250, 256, 0, stream>>>(wo, out, ws);
    k_softmax<<<64, 1024, 0, stream>>>(out, ws);
}

// Round 3
// 1271.159 us; speedup vs baseline: 6.9206x; 6.9206x over previous
//
#include <hip/hip_runtime.h>
#include <math.h>

#define H 512
#define D2 1024
#define D4 2048
#define E 1024
#define V 32000
#define M 32
#define N 4096
#define L 64
#define G3 (3*D4)   // 6144

// workspace layout (float offsets)
#define WS_H        0                      // 1024
#define WS_UAH      1024                   // 1024
#define WS_HSEQ     2048                   // 65*2048 = 133120
#define WS_GIW      135168                 // 64*6144 = 393216 (dead after steps; overlaid below)
#define WS_RW       528384                 // 64*1024 = 65536
#define WS_GH2      593920                 // 2 parity * 6144
#define WS_GIC0     606208                 // 2 * 6144
#define WS_GIC1     618496                 // 2 * 6144
#define WS_AT       630784                 // 128 floats: a0,a1 per step
#define WS_SP0      630912                 // 2 parity * 1024
#define WS_SP1      632960                 // 2 parity * 1024
#define WS_RT       635904                 // 512*64 (transposed r for logits GEMM)
#define WS_ANST     668672                 // 1024*64 (ans transposed)
// overlays of the dead WS_GIW region (valid only after the step loop):
#define WS_CT       WS_GIW                 // 1024*64 = 65536   (c_t columns, k-major)
#define WS_HST      (WS_GIW + 65536)       // 2048*64 = 131072  (h(t+1) columns, k-major)
#define WS_R3       (WS_GIW + 196608)      // 3*1024*64 = 196608 (K-split partials)
#define WS_BLOCKMAX WS_GIW                 // 64 rows * 256 block maxima (logits phase, after CT dead)
// bf16 weight caches (optional, if ws_size permits)
#define WS_WHHB     734208                 // 6144*2048 bf16 = 6291456 floats
#define WS_WIHCB    7025664                // 6144*1024 bf16 = 3145728 floats
#define WS_END_BF   10171392               // total floats with bf16 caches (~40.7 MB)

__device__ __forceinline__ float warpSum64(float v){
#pragma unroll
    for (int off = 32; off; off >>= 1) v += __shfl_xor(v, off, 64);
    return v;
}
__device__ __forceinline__ float dot4(float4 a, float4 b){
    return a.x*b.x + a.y*b.y + a.z*b.z + a.w*b.w;
}
__device__ __forceinline__ unsigned short f2bf(float f){
    unsigned u = __float_as_uint(f);
    u += 0x7fffu + ((u >> 16) & 1u);   // RNE
    return (unsigned short)(u >> 16);
}
__device__ __forceinline__ float bflo(unsigned u){ return __uint_as_float(u << 16); }
__device__ __forceinline__ float bfhi(unsigned u){ return __uint_as_float(u & 0xffff0000u); }

// ---------------- init: transpose ans, zero h ----------------
__global__ void k_init(const float* __restrict__ ans, float* __restrict__ ws){
    int b = blockIdx.x;
    if (b < L){
        for (int j = threadIdx.x; j < E; j += blockDim.x)
            ws[WS_ANST + j*L + b] = ans[b*E + j];
    } else {
        for (int i = threadIdx.x; i < D2; i += blockDim.x) ws[WS_H + i] = 0.f;
    }
}

// ---------------- one-time bf16 conversion of whh + wih c-half ----------------
__global__ __launch_bounds__(256) void k_cvt(const float* __restrict__ whh,
        const float* __restrict__ wih, float* __restrict__ ws){
    size_t idx = (size_t)blockIdx.x*blockDim.x + threadIdx.x;
    size_t nthr = (size_t)gridDim.x*blockDim.x;
    ushort4* dw = (ushort4*)(ws + WS_WHHB);
    const float4* s4 = (const float4*)whh;
    for (size_t i = idx; i < (size_t)G3*D4/4; i += nthr){
        float4 v = s4[i];
        ushort4 o; o.x = f2bf(v.x); o.y = f2bf(v.y); o.z = f2bf(v.z); o.w = f2bf(v.w);
        dw[i] = o;
    }
    ushort4* dc = (ushort4*)(ws + WS_WIHCB);
    const float4* w4 = (const float4*)wih;
    for (size_t i = idx; i < (size_t)G3*D2/4; i += nthr){
        size_t row = i / (D2/4), col = i - row*(D2/4);
        float4 v = w4[row*(D4/4) + (D2/4) + col];
        ushort4 o; o.x = f2bf(v.x); o.y = f2bf(v.y); o.z = f2bf(v.z); o.w = f2bf(v.w);
        dc[i] = o;
    }
}

// ---------------- h = colsum(h_q) + colsum(h_p) ----------------
__global__ void k_colsum(const float* __restrict__ hq, const float* __restrict__ hp,
                         float* __restrict__ ws){
    float4 acc = {0.f,0.f,0.f,0.f};
    int tid = threadIdx.x;
    for (int r = blockIdx.x; r < M + N; r += gridDim.x){
        const float* src = (r < M) ? (hq + (size_t)r*D2) : (hp + (size_t)(r-M)*D2);
        float4 v = ((const float4*)src)[tid];
        acc.x += v.x; acc.y += v.y; acc.z += v.z; acc.w += v.w;
    }
    float* h = ws + WS_H + tid*4;
    atomicAdd(h+0, acc.x); atomicAdd(h+1, acc.y);
    atomicAdd(h+2, acc.z); atomicAdd(h+3, acc.w);
}

// ---------------- u_a_h and d0 ----------------
__global__ __launch_bounds__(256) void k_uah_d0(
        const float* __restrict__ uaw, const float* __restrict__ wdw,
        const float* __restrict__ wdb, const float* __restrict__ hq,
        const float* __restrict__ hp, float* __restrict__ ws){
    int wid = blockIdx.x * (blockDim.x >> 6) + (threadIdx.x >> 6);
    int lane = threadIdx.x & 63;
    const float* Wrow; const float* x;
    if (wid < D2){ Wrow = uaw + (size_t)wid*D2; x = ws + WS_H; }
    else {
        int i = (wid - D2) & 1023;
        int r = (wid - D2) >> 10;
        Wrow = wdw + (size_t)i*D2;
        x = r ? hp : hq;
    }
    const float4* W4 = (const float4*)Wrow;
    const float4* x4 = (const float4*)x;
    float acc = 0.f;
#pragma unroll
    for (int m = 0; m < 4; m++){
        int j = lane + 64*m;
        acc += dot4(W4[j], x4[j]);
    }
    acc = warpSum64(acc);
    if (lane == 0){
        if (wid < D2) ws[WS_UAH + wid] = acc;
        else {
            int i = (wid - D2) & 1023, r = (wid - D2) >> 10;
            ws[WS_HSEQ + r*D2 + i] = tanhf(acc + wdb[i]);
        }
    }
}

// ---------------- pregemm as tiled GEMM (conflict-free, 224 blocks) ----------------
// C[7168][64] = W[7168][1024] @ ansT[1024][64]
// blocks 0..191: wih w-half 32-row tiles -> GIW (+bias); 192..223: wrw -> RW
__global__ __launch_bounds__(256) void k_pregemm(
        const float* __restrict__ wih, const float* __restrict__ bih,
        const float* __restrict__ wrw, float* __restrict__ ws){
    __shared__ float aR[32][68];    // [row][k] row-major: conflict-free stores, broadcast reads
    __shared__ float b_s[64][68];   // [k][t]
    int tid = threadIdx.x;
    int blk = blockIdx.x;
    bool isW = blk < 192;
    const float* src = isW ? wih : wrw;
    size_t stride = isW ? D4 : D2;
    int rbase = isW ? blk*32 : (blk-192)*32;
    int t0 = (tid & 15) * 4;
    int rg = (tid >> 4) * 2;
    float acc[4][2];
#pragma unroll
    for (int i = 0; i < 4; i++){ acc[i][0] = 0.f; acc[i][1] = 0.f; }

    const float* ansT = ws + WS_ANST;
    for (int kc = 0; kc < 1024; kc += 64){
        __syncthreads();
#pragma unroll
        for (int it = 0; it < 2; it++){
            int idx = it*256 + tid;
            int row = idx >> 4;
            int kq  = (idx & 15) * 4;
            float4 w = *(const float4*)(src + (size_t)(rbase + row)*stride + kc + kq);
            *(float4*)&aR[row][kq] = w;
        }
#pragma unroll
        for (int it = 0; it < 4; it++){
            int idx = it*256 + tid;
            int k = idx >> 4;
            int c4 = (idx & 15) * 4;
            *(float4*)&b_s[k][c4] = *(const float4*)(ansT + (size_t)(kc + k)*L + c4);
        }
        __syncthreads();
#pragma unroll 4
        for (int k = 0; k < 64; k++){
            float4 bb = *(float4*)&b_s[k][t0];
            float a0r = aR[rg][k], a1r = aR[rg+1][k];
            acc[0][0] += bb.x*a0r; acc[0][1] += bb.x*a1r;
            acc[1][0] += bb.y*a0r; acc[1][1] += bb.y*a1r;
            acc[2][0] += bb.z*a0r; acc[2][1] += bb.z*a1r;
            acc[3][0] += bb.w*a0r; acc[3][1] += bb.w*a1r;
        }
    }
#pragma unroll
    for (int i = 0; i < 4; i++){
#pragma unroll
        for (int j = 0; j < 2; j++){
            int r = rbase + rg + j;
            if (isW) ws[WS_GIW + (size_t)(t0+i)*G3 + r] = acc[i][j] + bih[r];
            else     ws[WS_RW  + (size_t)(t0+i)*D2 + r] = acc[i][j];
        }
    }
}

// ---------------- fused step kernel: one launch per step ----------------
// tasks per step (uniform ~2048-MAC granularity):
//   [0,1024) s 1-row dual | [1024,7168) gh | [7168,13312) giC
#define STEP_BLOCKS 256
#define STEP_THREADS 1024
#define NWAVES (STEP_BLOCKS*16)
#define STEP_TASKS 13312
__global__ __launch_bounds__(1024) void k_step(
        const float* __restrict__ whh, const float* __restrict__ bhh,
        const float* __restrict__ wih, const float* __restrict__ waw,
        const float* __restrict__ vw,  float* __restrict__ ws, int t, int use_bf){
    __shared__ float4 h4s[D4/4];
    __shared__ float red0[16];
    __shared__ float red1[16];
    __shared__ float sa[2];
    float* h_lds = (float*)h4s;
    int tid = threadIdx.x, lane = tid & 63, wv = tid >> 6;
    int par = t & 1, pprev = par ^ 1;

    // ---- a(t-1) from spart(t-1): dual 1024-element reduce, all 16 waves ----
    if (t >= 1){
        float x0 = ws[WS_SP0 + pprev*1024 + (wv << 6) + lane];
        float x1 = ws[WS_SP1 + pprev*1024 + (wv << 6) + lane];
        x0 = warpSum64(x0);
        x1 = warpSum64(x1);
        if (lane == 0){ red0[wv] = x0; red1[wv] = x1; }
        __syncthreads();
        if (tid == 0){
            float s0 = 0.f, s1 = 0.f;
#pragma unroll
            for (int i = 0; i < 16; i++){ s0 += red0[i]; s1 += red1[i]; }
            float mx = fmaxf(s0, s1);
            float e0 = expf(s0-mx), e1 = expf(s1-mx);
            sa[0] = e0/(e0+e1); sa[1] = e1/(e0+e1);
            if (blockIdx.x == 0){
                ws[WS_AT + (t-1)*2]     = sa[0];
                ws[WS_AT + (t-1)*2 + 1] = sa[1];
            }
        }
        __syncthreads();
    }
    float a0 = (t >= 1) ? sa[0] : 0.f;
    float a1 = (t >= 1) ? sa[1] : 0.f;

    // ---- reconstruct h(t) into LDS ----
    if (t == 0){
        for (int i = tid; i < D4; i += STEP_THREADS) h_lds[i] = ws[WS_HSEQ + i];
    } else {
        const float* hprev = ws + WS_HSEQ + (size_t)(t-1)*D4;
        const float* giw = ws + WS_GIW + (size_t)(t-1)*G3;
        const float* gh  = ws + WS_GH2  + pprev*G3;
        const float* g0  = ws + WS_GIC0 + pprev*G3;
        const float* g1  = ws + WS_GIC1 + pprev*G3;
        for (int k = tid; k < D4; k += STEP_THREADS){
            float gir = giw[k]      + a0*g0[k]      + a1*g1[k];
            float giz = giw[k+D4]   + a0*g0[k+D4]   + a1*g1[k+D4];
            float gin = giw[k+2*D4] + a0*g0[k+2*D4] + a1*g1[k+2*D4];
            float rr = 1.f/(1.f + expf(-(gir + gh[k])));
            float zz = 1.f/(1.f + expf(-(giz + gh[k+D4])));
            float nn = tanhf(gin + rr*gh[k+2*D4]);
            float hv = (1.f - zz)*nn + zz*hprev[k];
            h_lds[k] = hv;
            if (blockIdx.x == 0) ws[WS_HSEQ + (size_t)t*D4 + k] = hv;
        }
    }
    __syncthreads();

    if (t >= L) return;   // final launch only reconstructs h(64) / stores a(63)

    const float4* h4 = (const float4*)h_lds;
    int gw = blockIdx.x*16 + wv;
    for (int task = gw; task < STEP_TASKS; task += NWAVES){
        if (task < 1024){
            int i = task;               // s 1-row dual
            const float4* W4 = (const float4*)(waw + (size_t)i*D2);
            float ac0 = 0.f, ac1 = 0.f;
#pragma unroll
            for (int m = 0; m < 4; m++){
                int j = lane + 64*m;
                float4 w = W4[j];
                ac0 += dot4(w, h4[j]);
                ac1 += dot4(w, h4[256 + j]);
            }
            ac0 = warpSum64(ac0); ac1 = warpSum64(ac1);
            if (lane == 0){
                float u = ws[WS_UAH + i], vv = vw[i];
                ws[WS_SP0 + par*1024 + i] = vv * tanhf(ac0 + u);
                ws[WS_SP1 + par*1024 + i] = vv * tanhf(ac1 + u);
            }
        } else if (task < 7168){
            int k = task - 1024;     // gh
            float acc = 0.f;
            if (use_bf){
                const unsigned short* Wr = (const unsigned short*)(ws + WS_WHHB) + (size_t)k*D4;
#pragma unroll
                for (int m = 0; m < 4; m++){
                    int e = m*512 + lane*8;
                    uint4 w = *(const uint4*)(Wr + e);
                    float4 ha = h4[e>>2], hb = h4[(e>>2)+1];
                    acc += bflo(w.x)*ha.x + bfhi(w.x)*ha.y
                         + bflo(w.y)*ha.z + bfhi(w.y)*ha.w
                         + bflo(w.z)*hb.x + bfhi(w.z)*hb.y
                         + bflo(w.w)*hb.z + bfhi(w.w)*hb.w;
                }
            } else {
                const float4* W4 = (const float4*)(whh + (size_t)k*D4);
#pragma unroll
                for (int m = 0; m < 8; m++){
                    int j = lane + 64*m;
                    acc += dot4(W4[j], h4[j]);
                }
            }
            acc = warpSum64(acc);
            if (lane == 0) ws[WS_GH2 + par*G3 + k] = acc + bhh[k];
        } else {
            int k = task - 7168;     // giC dual (wih c-half)
            float ac0 = 0.f, ac1 = 0.f;
            if (use_bf){
                const unsigned short* Wr = (const unsigned short*)(ws + WS_WIHCB) + (size_t)k*D2;
#pragma unroll
                for (int m = 0; m < 2; m++){
                    int e = m*512 + lane*8;
                    uint4 w = *(const uint4*)(Wr + e);
                    float4 ha = h4[e>>2],       hb = h4[(e>>2)+1];
                    float4 hc = h4[256+(e>>2)], hd = h4[256+(e>>2)+1];
                    float f0 = bflo(w.x), f1 = bfhi(w.x), f2 = bflo(w.y), f3 = bfhi(w.y);
                    float f4 = bflo(w.z), f5 = bfhi(w.z), f6 = bflo(w.w), f7 = bfhi(w.w);
                    ac0 += f0*ha.x + f1*ha.y + f2*ha.z + f3*ha.w
                         + f4*hb.x + f5*hb.y + f6*hb.z + f7*hb.w;
                    ac1 += f0*hc.x + f1*hc.y + f2*hc.z + f3*hc.w
                         + f4*hd.x + f5*hd.y + f6*hd.z + f7*hd.w;
                }
            } else {
                const float4* W4 = (const float4*)(wih + (size_t)k*D4 + D2);
#pragma unroll
                for (int m = 0; m < 4; m++){
                    int j = lane + 64*m;
                    float4 w = W4[j];
                    ac0 += dot4(w, h4[j]);
                    ac1 += dot4(w, h4[256 + j]);
                }
            }
            ac0 = warpSum64(ac0); ac1 = warpSum64(ac1);
            if (lane == 0){
                ws[WS_GIC0 + par*G3 + k] = ac0;
                ws[WS_GIC1 + par*G3 + k] = ac1;
            }
        }
    }
}

// ---------------- prep for deferred r: build CT[k][t] and HST[k][t] ----------------
// CT[:,j] = a0(j)*h(j)[0:D2] + a1(j)*h(j)[D2:2*D2];  HST[:,j] = h(j+1)
__global__ __launch_bounds__(256) void k_prep(float* __restrict__ ws){
    int j = blockIdx.x;            // 0..63
    const float* hA = ws + WS_HSEQ + (size_t)j*D4;
    const float* hB = hA + D4;
    float a0 = ws[WS_AT + 2*j], a1 = ws[WS_AT + 2*j + 1];
    for (int k = threadIdx.x; k < D4; k += 256){
        ws[WS_HST + (size_t)k*64 + j] = hB[k];
        if (k < D2) ws[WS_CT + (size_t)k*64 + j] = a0*hA[k] + a1*hA[k + D2];
    }
}

// ---------------- deferred r GEMM: R_partial = Urw@CT (ks=0) | Vrw@HST halves (ks=1,2) ----
// grid 48 = 16 h-blocks x 3 K-splits; each block: 64 A-rows (32 top h + 32 bottom h+512) x 64 t
__global__ __launch_bounds__(512) void k_post(const float* __restrict__ urw,
        const float* __restrict__ vrw, float* __restrict__ ws){
    __shared__ float aR[64][68];
    __shared__ float bS[64][68];
    int tid = threadIdx.x;
    int hb = blockIdx.x & 15;
    int ks = blockIdx.x >> 4;          // 0: urw/CT; 1,2: vrw/HST halves
    int hbase = hb * 32;
    const float* A = (ks == 0) ? urw : vrw;
    size_t astride = (ks == 0) ? D2 : D4;
    int koff = (ks == 2) ? 1024 : 0;
    const float* B = ws + ((ks == 0) ? WS_CT : WS_HST) + (size_t)koff*64;
    int tg = tid & 15, vg = tid >> 4;   // vg in [0,32)
    int t0 = tg*4;
    int r0 = vg*2;
    float acc[2][4];
#pragma unroll
    for (int j = 0; j < 2; j++){ acc[j][0]=acc[j][1]=acc[j][2]=acc[j][3]=0.f; }

    for (int kc = 0; kc < 1024; kc += 64){
        __syncthreads();
#pragma unroll
        for (int it = 0; it < 2; it++){
            int idx = it*512 + tid;
            int r = idx >> 4;
            int kq = (idx & 15) * 4;
            int grow = (r < 32) ? (hbase + r) : (512 + hbase + (r - 32));
            *(float4*)&aR[r][kq] = *(const float4*)(A + (size_t)grow*astride + koff + kc + kq);
        }
#pragma unroll
        for (int it = 0; it < 2; it++){
            int idx = it*512 + tid;
            int k = idx >> 4;
            int c4 = (idx & 15)*4;
            *(float4*)&bS[k][c4] = *(const float4*)(B + (size_t)(kc + k)*64 + c4);
        }
        __syncthreads();
#pragma unroll 4
        for (int k = 0; k < 64; k++){
            float4 bb = *(float4*)&bS[k][t0];
            float a0 = aR[r0][k], a1 = aR[r0+1][k];
            acc[0][0]+=bb.x*a0; acc[0][1]+=bb.y*a0; acc[0][2]+=bb.z*a0; acc[0][3]+=bb.w*a0;
            acc[1][0]+=bb.x*a1; acc[1][1]+=bb.y*a1; acc[1][2]+=bb.z*a1; acc[1][3]+=bb.w*a1;
        }
    }
    float* R = ws + WS_R3 + (size_t)ks*65536;
#pragma unroll
    for (int j = 0; j < 2; j++){
        int r = r0 + j;
        int grow = (r < 32) ? (hbase + r) : (512 + hbase + (r - 32));
        float4 o = {acc[j][0], acc[j][1], acc[j][2], acc[j][3]};
        *(float4*)(R + (size_t)grow*64 + t0) = o;
    }
}

// ---------------- combine partials + RW, maxout -> RT (transposed for logits) ----------
__global__ __launch_bounds__(256) void k_rmax(float* __restrict__ ws){
    int tid = threadIdx.x;
    int h = blockIdx.x*16 + (tid >> 4);   // 32 blocks -> 512 h
    int t0 = (tid & 15)*4;
    const float* R = ws + WS_R3;
    float4 x0 = *(const float4*)(R + (size_t)h*64 + t0);
    float4 x1 = *(const float4*)(R + 65536 + (size_t)h*64 + t0);
    float4 x2 = *(const float4*)(R + 131072 + (size_t)h*64 + t0);
    float4 y0 = *(const float4*)(R + (size_t)(h+512)*64 + t0);
    float4 y1 = *(const float4*)(R + 65536 + (size_t)(h+512)*64 + t0);
    float4 y2 = *(const float4*)(R + 131072 + (size_t)(h+512)*64 + t0);
    float4 o;
    o.x = fmaxf(x0.x+x1.x+x2.x + ws[WS_RW + (size_t)(t0+0)*D2 + h],
                y0.x+y1.x+y2.x + ws[WS_RW + (size_t)(t0+0)*D2 + h + 512]);
    o.y = fmaxf(x0.y+x1.y+x2.y + ws[WS_RW + (size_t)(t0+1)*D2 + h],
                y0.y+y1.y+y2.y + ws[WS_RW + (size_t)(t0+1)*D2 + h + 512]);
    o.z = fmaxf(x0.z+x1.z+x2.z + ws[WS_RW + (size_t)(t0+2)*D2 + h],
                y0.z+y1.z+y2.z + ws[WS_RW + (size_t)(t0+2)*D2 + h + 512]);
    o.w = fmaxf(x0.w+x1.w+x2.w + ws[WS_RW + (size_t)(t0+3)*D2 + h],
                y0.w+y1.w+y2.w + ws[WS_RW + (size_t)(t0+3)*D2 + h + 512]);
    *(float4*)(ws + WS_RT + (size_t)h*L + t0) = o;
}

// ---------------- logits GEMM: out[t][v] = w_o[v] . r_t (tiled, coalesced) ----------------
__global__ __launch_bounds__(256) void k_logits(const float* __restrict__ wo,
        float* __restrict__ out, float* __restrict__ ws){
    __shared__ float a_s[64][132];
    __shared__ float b_s[64][68];
    __shared__ float lmax[64][16];
    int tid = threadIdx.x;
    int vbase = blockIdx.x * 128;
    int tg = tid & 15;
    int vg = tid >> 4;
    int t0 = tg * 4, v0 = vg * 8;
    float acc[4][8];
#pragma unroll
    for (int i = 0; i < 4; i++)
#pragma unroll
        for (int j = 0; j < 8; j++) acc[i][j] = 0.f;

    const float* rT = ws + WS_RT;
    for (int kc = 0; kc < 512; kc += 64){
        __syncthreads();
        {
            int col = (tid & 15) * 4;
            int rbase = tid >> 4;
#pragma unroll
            for (int it = 0; it < 8; it++){
                int r = it*16 + rbase;
                float4 w = *(const float4*)(wo + (size_t)(vbase + r)*H + kc + col);
                a_s[col+0][r] = w.x; a_s[col+1][r] = w.y;
                a_s[col+2][r] = w.z; a_s[col+3][r] = w.w;
            }
#pragma unroll
            for (int it = 0; it < 4; it++){
                int idx = it*256 + tid;
                int k = idx >> 4;
                int c4 = (idx & 15) * 4;
                *(float4*)&b_s[k][c4] = *(const float4*)(rT + (size_t)(kc + k)*L + c4);
            }
        }
        __syncthreads();
#pragma unroll 4
        for (int k = 0; k < 64; k++){
            float4 bb = *(float4*)&b_s[k][t0];
            float4 aa = *(float4*)&a_s[k][v0];
            float4 ab = *(float4*)&a_s[k][v0+4];
            float bv[4] = {bb.x, bb.y, bb.z, bb.w};
            float av[8] = {aa.x, aa.y, aa.z, aa.w, ab.x, ab.y, ab.z, ab.w};
#pragma unroll
            for (int i = 0; i < 4; i++)
#pragma unroll
                for (int j = 0; j < 8; j++) acc[i][j] += bv[i]*av[j];
        }
    }
#pragma unroll
    for (int i = 0; i < 4; i++){
        float m = acc[i][0];
#pragma unroll
        for (int j = 1; j < 8; j++) m = fmaxf(m, acc[i][j]);
        lmax[t0+i][vg] = m;
        float4 o1 = {acc[i][0], acc[i][1], acc[i][2], acc[i][3]};
        float4 o2 = {acc[i][4], acc[i][5], acc[i][6], acc[i][7]};
        float* dst = out + (size_t)(t0+i)*V + vbase + v0;
        *(float4*)dst = o1;
        *(float4*)(dst+4) = o2;
    }
    __syncthreads();
    if (tid < 64){
        float m = lmax[tid][0];
#pragma unroll
        for (int j = 1; j < 16; j++) m = fmaxf(m, lmax[tid][j]);
        ws[WS_BLOCKMAX + (size_t)tid*256 + blockIdx.x] = m;
    }
}

// ---------------- softmax per row ----------------
__global__ __launch_bounds__(1024) void k_softmax(float* __restrict__ out,
                                                  const float* __restrict__ ws){
    __shared__ float red[16];
    __shared__ float bcast;
    int t = blockIdx.x, tid = threadIdx.x;
    int lane = tid & 63, wv = tid >> 6;
    float m = -3.402823466e38f;
    if (tid < 250) m = ws[WS_BLOCKMAX + (size_t)t*256 + tid];
#pragma unroll
    for (int off = 32; off; off >>= 1) m = fmaxf(m, __shfl_xor(m, off, 64));
    if (lane == 0) red[wv] = m;
    __syncthreads();
    if (tid == 0){
        float mm = red[0];
        for (int i = 1; i < 16; i++) mm = fmaxf(mm, red[i]);
        bcast = mm;
    }
    __syncthreads();
    float rmax = bcast;
    float* row = out + (size_t)t*V;
    float4 e[8];
    float s = 0.f;
#pragma unroll
    for (int i = 0; i < 8; i++){
        int idx = tid + i*1024;
        if (idx < V/4){
            float4 x = ((const float4*)row)[idx];
            e[i].x = expf(x.x - rmax); e[i].y = expf(x.y - rmax);
            e[i].z = expf(x.z - rmax); e[i].w = expf(x.w - rmax);
            s += e[i].x + e[i].y + e[i].z + e[i].w;
        }
    }
#pragma unroll
    for (int off = 32; off; off >>= 1) s += __shfl_xor(s, off, 64);
    if (lane == 0) red[wv] = s;
    __syncthreads();
    if (tid == 0){
        float ss = 0.f;
        for (int i = 0; i < 16; i++) ss += red[i];
        bcast = 1.f/ss;
    }
    __syncthreads();
    float inv = bcast;
#pragma unroll
    for (int i = 0; i < 8; i++){
        int idx = tid + i*1024;
        if (idx < V/4){
            float4 p = e[i];
            p.x *= inv; p.y *= inv; p.z *= inv; p.w *= inv;
            ((float4*)row)[idx] = p;
        }
    }
}

extern "C" void kernel_launch(void* const* d_in, const int* in_sizes, int n_in,
                              void* d_out, int out_size, void* d_ws, size_t ws_size,
                              hipStream_t stream){
    const float* hq  = (const float*)d_in[0];
    const float* hp  = (const float*)d_in[1];
    const float* ans = (const float*)d_in[2];
    const float* vw  = (const float*)d_in[3];
    const float* wdw = (const float*)d_in[4];
    const float* wdb = (const float*)d_in[5];
    const float* waw = (const float*)d_in[6];
    const float* uaw = (const float*)d_in[7];
    const float* wrw = (const float*)d_in[8];
    const float* urw = (const float*)d_in[9];
    const float* vrw = (const float*)d_in[10];
    const float* wo  = (const float*)d_in[11];
    const float* wih = (const float*)d_in[12];
    const float* whh = (const float*)d_in[13];
    const float* bih = (const float*)d_in[14];
    const float* bhh = (const float*)d_in[15];
    float* out = (float*)d_out;
    float* ws  = (float*)d_ws;

    int use_bf = (ws_size >= (size_t)WS_END_BF * 4) ? 1 : 0;

    k_init<<<L+1, 256, 0, stream>>>(ans, ws);
    if (use_bf) k_cvt<<<1024, 256, 0, stream>>>(whh, wih, ws);
    k_colsum<<<256, 256, 0, stream>>>(hq, hp, ws);
    k_uah_d0<<<768, 256, 0, stream>>>(uaw, wdw, wdb, hq, hp, ws);
    k_pregemm<<<224, 256, 0, stream>>>(wih, bih, wrw, ws);

    for (int t = 0; t < L; t++)
        k_step<<<STEP_BLOCKS, STEP_THREADS, 0, stream>>>(whh, bhh, wih, waw, vw, ws, t, use_bf);
    k_step<<<1, STEP_THREADS, 0, stream>>>(whh, bhh, wih, waw, vw, ws, L, use_bf);

    k_prep<<<L, 256, 0, stream>>>(ws);
    k_post<<<48, 512, 0, stream>>>(urw, vrw, ws);
    k_rmax<<<32, 256, 0, stream>>>(ws);

    k_logits<<<250, 256, 0, stream>>>(wo, out, ws);
    k_softmax<<<64, 1024, 0, stream>>>(out, ws);
}